// Round 8
// baseline (444.689 us; speedup 1.0000x reference)
//
#include <hip/hip_runtime.h>
#include <cstdint>
#include <cstddef>

// ---------------------------------------------------------------------------
// y = x @ W^T + lb  [B=32768, C=2048], K=2048 ; GroupNorm(32 groups of 64) ;
// per-row min ; out[0,c,b,0] = mins[b] + final_bias[c].
//
// R8: (1) 3-buffer ring, ONE barrier per K-tile: tile u stages u+2 into
// buf (u-1)%3 (freed+drained at u-1's boundary) at the TOP of the tile ->
// full-tile latency cover, no mid-tile barrier. (2) convert-x fused into
// GEMM: A reg-staged from fp32 x (2x float4 -> f2bf x8 -> swizzled
// ds_write_b128); the 65us convert-x pass and its 134MB round trip are
// gone. W stays pre-converted bf16 (4us). (3) bijective block mapping
// groups the 8 bj-blocks of each bi onto ONE XCD as adjacent slots
// (bi=(blk&7)+8*(blk>>6), bj=(blk>>3)&7) so each fp32 x-panel is fetched
// by a single L2 exactly once (~268MB total instead of 4x).
// Per tile: {stage(u+2): A-gload+2x B-glds | R1 a0-3,b01 | Q1 | R2 b23 |
// vmcnt(2)+cvt+ds_write A | Q2 | lgkm0 (+vmcnt0 tail) | barrier}.
// ---------------------------------------------------------------------------

#define AS1C(p) ((const __attribute__((address_space(1))) void*)(p))
#define AS3(p)  ((__attribute__((address_space(3))) void*)(p))
#define SB0()   __builtin_amdgcn_sched_barrier(0)

typedef short  short8  __attribute__((ext_vector_type(8)));
typedef int    int4v   __attribute__((ext_vector_type(4)));
typedef float  f32x4   __attribute__((ext_vector_type(4)));
typedef unsigned short ushort8 __attribute__((ext_vector_type(8)));

static constexpr int BDIM = 32768;
static constexpr int KDIM = 2048;
static constexpr int CDIM = 2048;
static constexpr int NT   = KDIM / 32;    // 64 K-tiles of BK=32

// ----------------------------- helpers -------------------------------------

__device__ __forceinline__ unsigned short f2bf(float f) {
    unsigned u = __float_as_uint(f);
    u += 0x7FFFu + ((u >> 16) & 1u);   // RNE
    return (unsigned short)(u >> 16);
}

__device__ __forceinline__ ushort8 cvt8(float4 a, float4 b) {
    ushort8 o;
    o[0] = f2bf(a.x); o[1] = f2bf(a.y); o[2] = f2bf(a.z); o[3] = f2bf(a.w);
    o[4] = f2bf(b.x); o[5] = f2bf(b.y); o[6] = f2bf(b.z); o[7] = f2bf(b.w);
    return o;
}

__device__ __forceinline__ unsigned enc_min(float f) {
    unsigned u = __float_as_uint(f);
    return (u & 0x80000000u) ? ~u : (u | 0x80000000u);  // monotone float->uint
}

__device__ __forceinline__ float dec_min(unsigned e) {
    unsigned u = (e & 0x80000000u) ? (e ^ 0x80000000u) : ~e;
    return __uint_as_float(u);
}

// ----------------------------- k1: convert W --------------------------------

__global__ void convert_kernel(const float* __restrict__ src,
                               unsigned short* __restrict__ dst, int n8) {
    int i = blockIdx.x * blockDim.x + threadIdx.x;
    if (i >= n8) return;
    const float4* s4 = (const float4*)src;
    float4 a = s4[2 * i];
    float4 b = s4[2 * i + 1];
    *((ushort8*)dst + i) = cvt8(a, b);
}

// ------------------- k2: fused convert+GEMM+GroupNorm+row-min ---------------

__global__ __launch_bounds__(512, 4) void gemm_gn_min(
    const float* __restrict__ Af32,           // x [32768,2048] fp32 (d_in!)
    const unsigned short* __restrict__ Wbf,   // W [2048,2048]  bf16
    const float* __restrict__ lb,
    const float* __restrict__ gw,
    const float* __restrict__ gb,
    unsigned int* mins_enc)
{
    // buf d (24 KB): A at d*24576 (128 rows x 64B), B at d*24576+8192 (256x64B)
    __shared__ unsigned char lds[73728];      // 3 buffers

    const int tid  = threadIdx.x;
    const int wid  = tid >> 6;
    const int lane = tid & 63;

    // mapping: the 8 bj-blocks of one bi are adjacent dispatch slots on one
    // XCD (XCD = blk%8 round-robin) -> each x-panel fetched by exactly one L2.
    const int bi  = (blockIdx.x & 7) + ((blockIdx.x >> 6) << 3);   // 0..255
    const int bj  = (blockIdx.x >> 3) & 7;                          // 0..7
    const int row0 = bi * 128, col0 = bj * 256;
    const int wr = wid >> 2, wc = wid & 3;    // 2M x 4N, wave owns 64x64

    const int lrow = lane & 15;
    const int lq   = lane >> 4;               // K-chunk (16B) of this lane

    // ---- A reg-staging addressing (fp32 source, natural chunk; swizzle is
    // applied on the ds_write side): r_local = wid*16+(lane>>2), chunk lane&3.
    const int rloc = wid * 16 + (lane >> 2);
    const float* aSrcF = Af32 + (size_t)(row0 + rloc) * KDIM + (lane & 3) * 8;
    const int awOff = rloc * 64 + (((lane & 3) ^ ((lane >> 3) & 3)) << 4);

    // ---- B staging via global_load_lds (linear dest, inverse-swizzled src)
    const int schunk = (lane & 3) ^ ((lane >> 3) & 3);
    const unsigned short* bSrc =
        Wbf + (size_t)(col0 + wid * 16 + (lane >> 2)) * KDIM + schunk * 8;

    auto stageBh = [&](int d, int kt, int h) {
        __builtin_amdgcn_global_load_lds(
            AS1C(bSrc + (size_t)(h * 128) * KDIM + kt * 32),
            AS3(&lds[d * 24576 + 8192 + (h * 128 + wid * 16) * 64]), 16, 0, 0);
    };

    // read: row r, K-chunk lq -> physical chunk lq ^ ((r>>1)&3)
    auto rdA = [&](int d, int r) -> int4v {
        return *(const int4v*)&lds[d * 24576 + r * 64 +
                                   ((lq ^ ((r >> 1) & 3))) * 16];
    };
    auto rdB = [&](int d, int r) -> int4v {
        return *(const int4v*)&lds[d * 24576 + 8192 + r * 64 +
                                   ((lq ^ ((r >> 1) & 3))) * 16];
    };

    f32x4 acc[4][4] = {};
    int4v a[4], b[4];

    // ---- prologue: tiles 0 and 1. Issue order: Ag0, B0, Ag1, B1.
    float4 p00, p01, p10, p11;
    p00 = *(const float4*)(aSrcF);
    p01 = *(const float4*)(aSrcF + 4);
    SB0();
    stageBh(0, 0, 0); stageBh(0, 0, 1);
    SB0();
    p10 = *(const float4*)(aSrcF + 32);
    p11 = *(const float4*)(aSrcF + 36);
    SB0();
    stageBh(1, 1, 0); stageBh(1, 1, 1);
    SB0();
    asm volatile("s_waitcnt vmcnt(4)" ::: "memory");   // Ag0,B0 done
    *(ushort8*)&lds[0 * 24576 + awOff] = cvt8(p00, p01);
    asm volatile("s_waitcnt vmcnt(2)" ::: "memory");   // Ag1 done; B1 flies
    *(ushort8*)&lds[1 * 24576 + awOff] = cvt8(p10, p11);
    asm volatile("s_waitcnt lgkmcnt(0)" ::: "memory");
    __builtin_amdgcn_s_barrier();
    asm volatile("" ::: "memory");

    for (int t = 0; t < NT; ++t) {
        const int c = t % 3;
        const int sd = (t + 2) % 3;           // stage dest buf (== (t-1)%3)
        const bool st2 = (t + 2 < NT);
        float4 av0, av1;

        // -------- top: issue stage(t+2): A gloads to regs, B gload_lds
        if (st2) {
            const float* ap = aSrcF + (size_t)(t + 2) * 32;
            av0 = *(const float4*)ap;
            av1 = *(const float4*)(ap + 4);
        }
        SB0();
        if (st2) { stageBh(sd, t + 2, 0); stageBh(sd, t + 2, 1); }
        SB0();

        // -------- R1: a0-3 (4) + b01 (2) reads from buf c
#pragma unroll
        for (int m = 0; m < 4; ++m)
            a[m] = rdA(c, wr * 64 + m * 16 + lrow);
#pragma unroll
        for (int n = 0; n < 2; ++n)
            b[n] = rdB(c, wc * 64 + n * 16 + lrow);
        SB0();
        // -------- Q1: m0-3 x n0-1 (compiler-counted lgkm gates a/b01)
        __builtin_amdgcn_s_setprio(1);
#pragma unroll
        for (int m = 0; m < 4; ++m)
#pragma unroll
            for (int n = 0; n < 2; ++n)
                acc[m][n] = __builtin_amdgcn_mfma_f32_16x16x32_bf16(
                    __builtin_bit_cast(short8, a[m]),
                    __builtin_bit_cast(short8, b[n]),
                    acc[m][n], 0, 0, 0);
        __builtin_amdgcn_s_setprio(0);
        SB0();
        // -------- R2: b23 (2) reads
#pragma unroll
        for (int n = 2; n < 4; ++n)
            b[n] = rdB(c, wc * 64 + n * 16 + lrow);
        SB0();
        // -------- cvt + swizzled ds_write of A(t+2); drains B(t+1) too
        if (st2) {
            asm volatile("s_waitcnt vmcnt(2)" ::: "memory");
            *(ushort8*)&lds[sd * 24576 + awOff] = cvt8(av0, av1);
        }
        SB0();
        // -------- Q2: m0-3 x n2-3
        __builtin_amdgcn_s_setprio(1);
#pragma unroll
        for (int m = 0; m < 4; ++m)
#pragma unroll
            for (int n = 2; n < 4; ++n)
                acc[m][n] = __builtin_amdgcn_mfma_f32_16x16x32_bf16(
                    __builtin_bit_cast(short8, a[m]),
                    __builtin_bit_cast(short8, b[n]),
                    acc[m][n], 0, 0, 0);
        __builtin_amdgcn_s_setprio(0);
        SB0();
        // -------- boundary: reads+writes drained; tail drains last B stage
        asm volatile("s_waitcnt lgkmcnt(0)" ::: "memory");
        if (!st2) asm volatile("s_waitcnt vmcnt(0)" ::: "memory");
        __builtin_amdgcn_s_barrier();
        asm volatile("" ::: "memory");
    }

    // ---- epilogue: +bias, groupnorm over this wave's 64-col group, row min
    float lbv[4], gwv[4], gbv[4];
    const int cbase = col0 + wc * 64 + lrow;
#pragma unroll
    for (int n = 0; n < 4; ++n) {
        int ch = cbase + n * 16;
        lbv[n] = lb[ch]; gwv[n] = gw[ch]; gbv[n] = gb[ch];
    }

#pragma unroll
    for (int m = 0; m < 4; ++m) {
#pragma unroll
        for (int i = 0; i < 4; ++i) {
            float v[4];
            float s1 = 0.f, s2 = 0.f;
#pragma unroll
            for (int n = 0; n < 4; ++n) {
                v[n] = acc[m][n][i] + lbv[n];
                s1 += v[n];
                s2 += v[n] * v[n];
            }
#pragma unroll
            for (int mask = 1; mask <= 8; mask <<= 1) {
                s1 += __shfl_xor(s1, mask, 64);
                s2 += __shfl_xor(s2, mask, 64);
            }
            float mean = s1 * (1.f / 64.f);
            float var  = s2 * (1.f / 64.f) - mean * mean;
            float rstd = rsqrtf(var + 1e-5f);
            float mn = 3.4e38f;
#pragma unroll
            for (int n = 0; n < 4; ++n) {
                float nv = (v[n] - mean) * rstd * gwv[n] + gbv[n];
                mn = fminf(mn, nv);
            }
#pragma unroll
            for (int mask = 1; mask <= 8; mask <<= 1)
                mn = fminf(mn, __shfl_xor(mn, mask, 64));
            if (lrow == 0) {
                int row = row0 + wr * 64 + m * 16 + lq * 4 + i;
                atomicMin(mins_enc + row, enc_min(mn));
            }
        }
    }
}

// --------------------------- k3: broadcast ----------------------------------

__global__ void finalize_kernel(const unsigned int* mins_enc,
                                const float* __restrict__ fb, float* out) {
    size_t t = (size_t)blockIdx.x * 256 + threadIdx.x;
    size_t flat = t * 4;                      // 4 consecutive b, same c
    int c = (int)(flat >> 15);
    if (c == 1088) return;                    // mins live here; fixup later
    int b = (int)(flat & 32767);
    uint4 e = *(const uint4*)(mins_enc + b);
    float bias = fb[c];
    float4 o;
    o.x = dec_min(e.x) + bias;
    o.y = dec_min(e.y) + bias;
    o.z = dec_min(e.z) + bias;
    o.w = dec_min(e.w) + bias;
    *(float4*)(out + flat) = o;
}

__global__ void fixup_kernel(const float* __restrict__ fb, float* out) {
    int b = blockIdx.x * 256 + threadIdx.x;
    size_t idx = (size_t)1088 * 32768 + b;
    unsigned e = ((const unsigned*)out)[idx];  // read own cell first
    out[idx] = dec_min(e) + fb[1088];
}

// ----------------------------- launcher -------------------------------------

extern "C" void kernel_launch(void* const* d_in, const int* in_sizes, int n_in,
                              void* d_out, int out_size, void* d_ws, size_t ws_size,
                              hipStream_t stream) {
    const float* x  = (const float*)d_in[0];
    const float* w  = (const float*)d_in[1];
    const float* lb = (const float*)d_in[2];
    const float* gw = (const float*)d_in[3];
    const float* gb = (const float*)d_in[4];
    const float* fb = (const float*)d_in[5];
    float* out = (float*)d_out;

    // scratch inside d_out: W bf16 at [128 MiB, 136 MiB); mins at the
    // c==1088 output row = bytes [136 MiB, 136 MiB + 128 KiB) -- disjoint.
    unsigned short* wb = (unsigned short*)((char*)d_out + 134217728);
    unsigned int* mins = (unsigned int*)((char*)d_out + (size_t)1088 * 32768 * 4);

    // k1: W fp32 -> bf16 (8 MiB, ~4us)
    {
        int n8 = (CDIM * KDIM) / 8;
        convert_kernel<<<(n8 + 255) / 256, 256, 0, stream>>>(w, wb, n8);
    }

    // init encoded mins to 0xFFFFFFFF (>= every encoding)
    hipMemsetAsync((void*)mins, 0xFF, (size_t)BDIM * 4, stream);

    // k2: fused convert+GEMM+GN+min  (128x256 tiles -> 256x8 = 2048 blocks)
    gemm_gn_min<<<dim3((BDIM / 128) * (CDIM / 256)), dim3(512), 0, stream>>>(
        x, wb, lb, gw, gb, mins);

    // k3: broadcast (skips c==1088), then fixup c==1088
    finalize_kernel<<<(BDIM / 4) * CDIM / 256, 256, 0, stream>>>(mins, fb, out);
    fixup_kernel<<<BDIM / 256, 256, 0, stream>>>(fb, out);
}